// Round 1
// baseline (273.321 us; speedup 1.0000x reference)
//
#include <hip/hip_runtime.h>

#define N_NODES 50000
#define N_EDGES 800000
#define D_IN    128
#define D_OUT   64

// ---------------- Phase 1: support = x @ W  (f32 vector FMA) ----------------
// 16 nodes per 256-thread block; W (32KB) + x-tile (8KB) in LDS.
// thread (g,f): g = wave id (4 waves), f = lane (64). Each thread computes
// out[node0 + g*4 + j][f] for j=0..3 (4 independent accumulators for ILP).
#define NPB 16

__global__ __launch_bounds__(256) void gemm_xw(
    const float* __restrict__ x, const float* __restrict__ W,
    float* __restrict__ support) {
  __shared__ float Wlds[D_IN][D_OUT];   // 32 KiB
  __shared__ float xlds[NPB][D_IN];     //  8 KiB
  const int tid = threadIdx.x;
  const int node0 = blockIdx.x * NPB;

  // cooperative float4 loads: W = 2048 float4, x-tile = 512 float4
  const float4* W4 = (const float4*)W;
  float4* Wl4 = (float4*)Wlds;
#pragma unroll
  for (int i = 0; i < (D_IN * D_OUT / 4) / 256; ++i)
    Wl4[tid + i * 256] = W4[tid + i * 256];

  const float4* x4 = (const float4*)(x + (size_t)node0 * D_IN);
  float4* xl4 = (float4*)xlds;
#pragma unroll
  for (int i = 0; i < (NPB * D_IN / 4) / 256; ++i)
    xl4[tid + i * 256] = x4[tid + i * 256];

  __syncthreads();

  const int f = tid & 63;        // output feature (coalesced, 2-way LDS = free)
  const int g = tid >> 6;        // wave id -> node sub-group (broadcast reads)
  float acc0 = 0.f, acc1 = 0.f, acc2 = 0.f, acc3 = 0.f;

#pragma unroll
  for (int k = 0; k < D_IN; k += 4) {
    const float w0 = Wlds[k + 0][f];
    const float w1 = Wlds[k + 1][f];
    const float w2 = Wlds[k + 2][f];
    const float w3 = Wlds[k + 3][f];
    const float4 xa = *(const float4*)&xlds[g * 4 + 0][k];
    const float4 xb = *(const float4*)&xlds[g * 4 + 1][k];
    const float4 xc = *(const float4*)&xlds[g * 4 + 2][k];
    const float4 xd = *(const float4*)&xlds[g * 4 + 3][k];
    acc0 += xa.x * w0 + xa.y * w1 + xa.z * w2 + xa.w * w3;
    acc1 += xb.x * w0 + xb.y * w1 + xb.z * w2 + xb.w * w3;
    acc2 += xc.x * w0 + xc.y * w1 + xc.z * w2 + xc.w * w3;
    acc3 += xd.x * w0 + xd.y * w1 + xd.z * w2 + xd.w * w3;
  }

  const int nbase = node0 + g * 4;
  support[(size_t)(nbase + 0) * D_OUT + f] = acc0;
  support[(size_t)(nbase + 1) * D_OUT + f] = acc1;
  support[(size_t)(nbase + 2) * D_OUT + f] = acc2;
  support[(size_t)(nbase + 3) * D_OUT + f] = acc3;
}

// ---------------- Phase 2: scatter  out[dst] += val * support[src] ----------
// One 64-lane group per edge, EPG edges per group (prefetched). Gather and
// atomic target are 256B-contiguous per edge -> fully coalesced; atomics are
// fire-and-forget f32, avg 16 edges/dst so low contention.
#define EPG 8

__global__ __launch_bounds__(256) void scatter_edges(
    const float* __restrict__ support, const int* __restrict__ esrc,
    const int* __restrict__ edst, const float* __restrict__ eval,
    float* __restrict__ out, int n_edges) {
  const int tid = threadIdx.x;
  const int f = tid & 63;
  const int grp = blockIdx.x * 4 + (tid >> 6);
  const int e0 = grp * EPG;

  int s[EPG], d[EPG];
  float v[EPG];
#pragma unroll
  for (int i = 0; i < EPG; ++i) {
    const int e = e0 + i;
    if (e < n_edges) {
      s[i] = esrc[e];
      d[i] = edst[e];
      v[i] = eval[e];
    } else {
      s[i] = 0; d[i] = 0; v[i] = 0.f;
    }
  }
  float m[EPG];
#pragma unroll
  for (int i = 0; i < EPG; ++i)
    m[i] = support[(size_t)s[i] * D_OUT + f] * v[i];
#pragma unroll
  for (int i = 0; i < EPG; ++i) {
    if (e0 + i < n_edges)
      atomicAdd(&out[(size_t)d[i] * D_OUT + f], m[i]);
  }
}

// ---------------- Phase 3: out = relu(out + b), in place, float4 ------------
__global__ __launch_bounds__(256) void bias_relu(
    float* __restrict__ out, const float* __restrict__ b) {
  const int i = blockIdx.x * 256 + threadIdx.x;   // over N_NODES*D_OUT/4
  float4* o4 = (float4*)out;
  float4 v = o4[i];
  const int fb = (i * 4) & 63;                    // 4 | 64 -> contiguous bias
  const float4 bb = *(const float4*)&b[fb];
  v.x = fmaxf(v.x + bb.x, 0.f);
  v.y = fmaxf(v.y + bb.y, 0.f);
  v.z = fmaxf(v.z + bb.z, 0.f);
  v.w = fmaxf(v.w + bb.w, 0.f);
  o4[i] = v;
}

extern "C" void kernel_launch(void* const* d_in, const int* in_sizes, int n_in,
                              void* d_out, int out_size, void* d_ws, size_t ws_size,
                              hipStream_t stream) {
  const float* x    = (const float*)d_in[0];
  const int*   esrc = (const int*)  d_in[1];
  const int*   edst = (const int*)  d_in[2];
  const float* eval = (const float*)d_in[3];
  const float* W    = (const float*)d_in[4];
  const float* b    = (const float*)d_in[5];
  float* out     = (float*)d_out;
  float* support = (float*)d_ws;   // 50000*64*4 = 12.8 MB scratch

  const int n_edges = in_sizes[1];

  // out is poisoned 0xAA every timed call -> zero it for atomic accumulation
  hipMemsetAsync(d_out, 0, (size_t)N_NODES * D_OUT * sizeof(float), stream);

  gemm_xw<<<N_NODES / NPB, 256, 0, stream>>>(x, W, support);

  const int groups = (n_edges + EPG - 1) / EPG;
  scatter_edges<<<(groups + 3) / 4, 256, 0, stream>>>(
      support, esrc, edst, eval, out, n_edges);

  bias_relu<<<N_NODES * D_OUT / 4 / 256, 256, 0, stream>>>(out, b);
}